// Round 7
// baseline (187.891 us; speedup 1.0000x reference)
//
#include <hip/hip_runtime.h>

#define N_PP   8192
#define N_A    8192
#define DIM    16
#define NEDGE  262144
#define LOG2E  1.4426950408889634f

// ---- ws float-unit layout (~1.8 MB) ----
// [0..3]=accums (nonlink_pp, link_pp, nonlink_ap, link_ap), [4]=counter.
// bf16 rows padded to 64 B (u32[0..7]=data, [8..15]=0) -> branchless quad loads.
#define WS_PSBF 64
#define WS_PBF  (WS_PSBF + 131072)
#define WS_ABF  (WS_PBF  + 131072)
#define WS_X2PS (WS_ABF  + 131072)
#define WS_Y2P  (WS_X2PS + 8192)
#define WS_Y2A  (WS_Y2P  + 8192)
#define WS_EGC  (WS_Y2A  + 8192)   // exp(gamma_pp[8192+j])
#define WS_EBC  (WS_EGC  + 8192)   // exp(beta_ap[8192+j])
#define WS_GL2  (WS_EBC  + 8192)   // gamma_pp[i] * LOG2E  (pp row bias)
#define WS_BL2  (WS_GL2  + 8192)   // beta_ap[i]  * LOG2E  (ap row bias)

// Block map (256-thread blocks = 4 waves). Wave = (strip, 1-of-8 t-range).
// [0,1024) ap matrix; [1024,2048) pp matrix (longest strip first);
// [2048,2304) pp edges; [2304,2560) ap edges.
#define NB_MAT_AP 1024
#define NB_MAT_PP 1024
#define NB_EPP    256
#define NB_EAP    256
#define NB_TOTAL  (NB_MAT_AP + NB_MAT_PP + NB_EPP + NB_EAP)

typedef short    bf16x8 __attribute__((ext_vector_type(8)));
typedef float    f32x4  __attribute__((ext_vector_type(4)));
typedef unsigned u32x4  __attribute__((ext_vector_type(4)));

__device__ __forceinline__ float waveReduce(float v) {
#pragma unroll
    for (int off = 32; off > 0; off >>= 1)
        v += __shfl_down(v, off, 64);
    return v;
}

__device__ __forceinline__ unsigned bf16_rne(float f) {
    unsigned u = __builtin_bit_cast(unsigned, f);
    return (u + 0x7FFFu + ((u >> 16) & 1u)) >> 16;
}
__device__ __forceinline__ unsigned packbf2(float a, float b) {
    return bf16_rne(a) | (bf16_rne(b) << 16);
}

// 224 blocks x 256: [0,24576) row conversions; [24576,57344) bias arrays.
__global__ __launch_bounds__(256) void precompute_kernel(
    const float* __restrict__ p_star, const float* __restrict__ p,
    const float* __restrict__ a, const float* __restrict__ beta_ap,
    const float* __restrict__ gamma_pp, float* __restrict__ ws)
{
    const int g = blockIdx.x * 256 + threadIdx.x;
    if (g < 8) ws[g] = 0.0f;

    if (g < 3 * 8192) {
        const int arr = g >> 13, idx = g & 8191;
        const float* src = arr == 0 ? p_star : (arr == 1 ? p : a);
        const int bfo = arr == 0 ? WS_PSBF : (arr == 1 ? WS_PBF : WS_ABF);
        const int n2o = arr == 0 ? WS_X2PS : (arr == 1 ? WS_Y2P : WS_Y2A);
        const float4* rp = (const float4*)(src + idx * DIM);
        float4 f0 = rp[0], f1 = rp[1], f2 = rp[2], f3 = rp[3];
        float n2 = f0.x*f0.x + f0.y*f0.y + f0.z*f0.z + f0.w*f0.w
                 + f1.x*f1.x + f1.y*f1.y + f1.z*f1.z + f1.w*f1.w
                 + f2.x*f2.x + f2.y*f2.y + f2.z*f2.z + f2.w*f2.w
                 + f3.x*f3.x + f3.y*f3.y + f3.z*f3.z + f3.w*f3.w;
        u32x4 u0 = { packbf2(f0.x, f0.y), packbf2(f0.z, f0.w),
                     packbf2(f1.x, f1.y), packbf2(f1.z, f1.w) };
        u32x4 u1 = { packbf2(f2.x, f2.y), packbf2(f2.z, f2.w),
                     packbf2(f3.x, f3.y), packbf2(f3.z, f3.w) };
        u32x4 z  = { 0u, 0u, 0u, 0u };
        u32x4* dst = (u32x4*)(ws + bfo) + idx * 4;
        dst[0] = u0; dst[1] = u1; dst[2] = z; dst[3] = z;
        ws[n2o + idx] = n2;
    } else if (g < 7 * 8192) {
        const int h = g - 3 * 8192, q = h >> 13, i = h & 8191;
        if      (q == 0) ws[WS_EGC + i] = __expf(gamma_pp[8192 + i]);
        else if (q == 1) ws[WS_EBC + i] = __expf(beta_ap[8192 + i]);
        else if (q == 2) ws[WS_GL2 + i] = gamma_pp[i] * LOG2E;
        else             ws[WS_BL2 + i] = beta_ap[i] * LOG2E;
    }
}

// (256,4): allow up to 128 VGPRs so the ILP-4 batch (12 in-flight loads,
// ~48 dest VGPRs) is NOT serialized by register reuse. R6 showed the
// default allocator squeezing to 64 VGPRs and serializing the loads.
__global__ __launch_bounds__(256, 4) void main_kernel(
    const float* __restrict__ p_star, const float* __restrict__ p,
    const float* __restrict__ a, const float* __restrict__ beta_ap,
    const float* __restrict__ gamma_pp, const int* __restrict__ edges_pp,
    const int* __restrict__ edges_ap, float* __restrict__ ws,
    float* __restrict__ out)
{
    __shared__ float smred[4];
    const int b = blockIdx.x, tid = threadIdx.x, wid = tid >> 6;
    const int lane = tid & 63, quad = lane >> 4, l16 = lane & 15;

    float val = 0.f;
    int slot;

    if (b < NB_MAT_AP + NB_MAT_PP) {
        const bool isPP = (b >= NB_MAT_AP);
        const int  bb   = isPP ? b - NB_MAT_AP : b;
        const int  s    = isPP ? 511 - (bb >> 1) : (bb >> 1);   // pp longest-first
        const int  w    = ((bb & 1) << 2) + wid;                // 0..7
        slot = isPP ? 0 : 2;

        const unsigned* Xbf = (const unsigned*)(ws + WS_PSBF);
        const unsigned* Ybf = (const unsigned*)(ws + (isPP ? WS_PBF : WS_ABF));
        const float* x2  = ws + WS_X2PS;
        const float* y2  = ws + (isPP ? WS_Y2P : WS_Y2A);
        const float* gl2 = ws + (isPP ? WS_GL2 : WS_BL2);
        const float* EcA = ws + (isPP ? WS_EGC : WS_EBC);

        const int j = (s << 4) + l16;
        const bf16x8 bfrag =
            __builtin_bit_cast(bf16x8, *(const u32x4*)(Ybf + j * 16 + (quad << 2)));
        const float y2c = y2[j];
        const float Ec  = EcA[j];
        const f32x4 zero4 = {0.f, 0.f, 0.f, 0.f};

        // contiguous t-range for this wave
        int cnt, t;
        if (isPP) {             // full tiles t in [0,s); wave 7 adds diagonal
            const int base = s >> 3, rem = s & 7;
            cnt = base + (w < rem ? 1 : 0);
            t   = w * base + (w < rem ? w : rem);
        } else {                // 512 tiles, 64 per wave
            cnt = 64; t = w << 6;
        }

        float acc0 = 0.f, acc1 = 0.f, acc2 = 0.f, acc3 = 0.f;
        while (cnt >= 4) {      // 4 independent tiles per iteration (ILP)
            u32x4 au[4]; f32x4 ax2[4], ag[4];
#pragma unroll
            for (int k = 0; k < 4; ++k) {
                const int i0 = (t + k) << 4;
                au[k]  = *(const u32x4*)(Xbf + (i0 + l16) * 16 + (quad << 2));
                ax2[k] = *(const f32x4*)(x2  + i0 + (quad << 2));
                ag[k]  = *(const f32x4*)(gl2 + i0 + (quad << 2));
            }
            f32x4 d[4];
#pragma unroll
            for (int k = 0; k < 4; ++k)
                d[k] = __builtin_amdgcn_mfma_f32_16x16x32_bf16(
                    __builtin_bit_cast(bf16x8, au[k]), bfrag, zero4, 0, 0, 0);
            float pacc[4] = {0.f, 0.f, 0.f, 0.f};
#pragma unroll
            for (int k = 0; k < 4; ++k) {
#pragma unroll
                for (int r = 0; r < 4; ++r) {
                    float d2 = fmaf(-2.f, d[k][r], ax2[k][r] + y2c);
                    d2 = fmaxf(d2, 0.f);
                    float arg = fmaf(-LOG2E, __builtin_amdgcn_sqrtf(d2), ag[k][r]);
                    pacc[k] += __builtin_amdgcn_exp2f(arg);
                }
            }
            acc0 += pacc[0]; acc1 += pacc[1]; acc2 += pacc[2]; acc3 += pacc[3];
            t += 4; cnt -= 4;
        }
        while (cnt > 0) {       // wave-uniform remainder (<=3 tiles)
            const int i0 = t << 4;
            u32x4 au  = *(const u32x4*)(Xbf + (i0 + l16) * 16 + (quad << 2));
            f32x4 ax2 = *(const f32x4*)(x2  + i0 + (quad << 2));
            f32x4 ag  = *(const f32x4*)(gl2 + i0 + (quad << 2));
            f32x4 d = __builtin_amdgcn_mfma_f32_16x16x32_bf16(
                __builtin_bit_cast(bf16x8, au), bfrag, zero4, 0, 0, 0);
#pragma unroll
            for (int r = 0; r < 4; ++r) {
                float d2 = fmaf(-2.f, d[r], ax2[r] + y2c);
                d2 = fmaxf(d2, 0.f);
                acc0 += __builtin_amdgcn_exp2f(
                    fmaf(-LOG2E, __builtin_amdgcn_sqrtf(d2), ag[r]));
            }
            ++t; --cnt;
        }
        if (isPP && w == 7) {   // peeled diagonal tile t=s, strict j>i mask
            const int i0 = s << 4;
            u32x4 au  = *(const u32x4*)(Xbf + (i0 + l16) * 16 + (quad << 2));
            f32x4 ax2 = *(const f32x4*)(x2  + i0 + (quad << 2));
            f32x4 ag  = *(const f32x4*)(gl2 + i0 + (quad << 2));
            f32x4 d = __builtin_amdgcn_mfma_f32_16x16x32_bf16(
                __builtin_bit_cast(bf16x8, au), bfrag, zero4, 0, 0, 0);
#pragma unroll
            for (int r = 0; r < 4; ++r) {
                float d2 = fmaf(-2.f, d[r], ax2[r] + y2c);
                d2 = fmaxf(d2, 0.f);
                float term = __builtin_amdgcn_exp2f(
                    fmaf(-LOG2E, __builtin_amdgcn_sqrtf(d2), ag[r]));
                if (l16 <= (quad << 2) + r) term = 0.f;
                acc1 += term;
            }
        }
        val = ((acc0 + acc1) + (acc2 + acc3)) * Ec;
    } else {
        const int  eb   = b - (NB_MAT_AP + NB_MAT_PP);
        const bool isPP = (eb < NB_EPP);
        const int  base = (isPP ? eb : eb - NB_EPP) * 256 + tid;  // [0,65536)
        slot = isPP ? 1 : 3;
        float sum = 0.f;
#pragma unroll
        for (int k = 0; k < 4; ++k) {
            const int e = base + k * 65536;
            const float* yrow;
            float bias;
            int e0;
            if (isPP) {
                e0 = edges_pp[e];
                int e1 = edges_pp[NEDGE + e];
                yrow = p + e1 * DIM;
                bias = gamma_pp[e0] + gamma_pp[N_PP + e1];
            } else {
                e0 = edges_ap[e];
                int e1 = edges_ap[NEDGE + e];
                yrow = a + (e1 - N_PP) * DIM;
                bias = beta_ap[e0] + beta_ap[e1];
            }
            const float4* xp = (const float4*)(p_star + e0 * DIM);
            const float4* yp = (const float4*)yrow;
            float d2 = 0.f;
#pragma unroll
            for (int kk = 0; kk < 4; ++kk) {
                float4 xv = xp[kk], yv = yp[kk];
                float dx = xv.x - yv.x, dy = xv.y - yv.y,
                      dz = xv.z - yv.z, dw = xv.w - yv.w;
                d2 += dx*dx + dy*dy + dz*dz + dw*dw;
            }
            sum += bias - __builtin_amdgcn_sqrtf(d2);
        }
        val = sum;
    }

    float wsum = waveReduce(val);
    if ((tid & 63) == 0) smred[wid] = wsum;
    __syncthreads();
    if (tid == 0) {
        atomicAdd(&ws[slot], smred[0] + smred[1] + smred[2] + smred[3]);
        __threadfence();
        unsigned old = atomicAdd((unsigned*)(ws + 4), 1u);
        if (old == NB_TOTAL - 1) {
            float s0 = atomicAdd(&ws[0], 0.f), s1 = atomicAdd(&ws[1], 0.f);
            float s2 = atomicAdd(&ws[2], 0.f), s3 = atomicAdd(&ws[3], 0.f);
            out[0] = 0.5f * (s0 - s1) / (float)N_PP
                   + 0.5f * (s2 - s3) / (float)N_A;
        }
    }
}

extern "C" void kernel_launch(void* const* d_in, const int* in_sizes, int n_in,
                              void* d_out, int out_size, void* d_ws, size_t ws_size,
                              hipStream_t stream) {
    const float* p_star   = (const float*)d_in[0];
    const float* p        = (const float*)d_in[1];
    const float* a        = (const float*)d_in[2];
    const float* beta_ap  = (const float*)d_in[3];
    const float* gamma_pp = (const float*)d_in[4];
    const int*   edges_pp = (const int*)d_in[5];
    const int*   edges_ap = (const int*)d_in[6];

    float* ws  = (float*)d_ws;
    float* out = (float*)d_out;

    hipLaunchKernelGGL(precompute_kernel, dim3(224), dim3(256), 0, stream,
                       p_star, p, a, beta_ap, gamma_pp, ws);
    hipLaunchKernelGGL(main_kernel, dim3(NB_TOTAL), dim3(256), 0, stream,
                       p_star, p, a, beta_ap, gamma_pp, edges_pp, edges_ap, ws, out);
}

// Round 8
// 146.040 us; speedup vs baseline: 1.2866x; 1.2866x over previous
//
#include <hip/hip_runtime.h>
#include <stdint.h>

#define N_PP   8192
#define N_A    8192
#define DIM    16
#define NEDGE  262144
#define LOG2E  1.4426950408889634f
#define CH     32      // tiles per staged chunk

// ---- ws float-unit layout (~1.05 MB) ----
// [0..3]=accums (nonlink_pp, link_pp, nonlink_ap, link_ap), [4]=counter.
// bf16 rows are UNPADDED 32 B (8 u32) — LDS-staging needs contiguity.
#define WS_PSBF 64
#define WS_PBF  (WS_PSBF + 65536)
#define WS_ABF  (WS_PBF  + 65536)
#define WS_X2PS (WS_ABF  + 65536)
#define WS_Y2P  (WS_X2PS + 8192)
#define WS_Y2A  (WS_Y2P  + 8192)
#define WS_EGC  (WS_Y2A  + 8192)   // exp(gamma_pp[8192+j])
#define WS_EBC  (WS_EGC  + 8192)   // exp(beta_ap[8192+j])
#define WS_GL2  (WS_EBC  + 8192)   // gamma_pp[i] * LOG2E
#define WS_BL2  (WS_GL2  + 8192)   // beta_ap[i]  * LOG2E

// Blocks (256 thr = 4 waves). Matrix block = strip-group g (4 strips, wave w
// takes strip 4g+w) x t-quarter q. [0,512) ap; [512,1024) pp (longest-first);
// then 256+256 edge blocks.
#define NB_AP  512
#define NB_PP  512
#define NB_EPP 256
#define NB_EAP 256
#define NB_TOTAL (NB_AP + NB_PP + NB_EPP + NB_EAP)

typedef short    bf16x8 __attribute__((ext_vector_type(8)));
typedef float    f32x4  __attribute__((ext_vector_type(4)));
typedef unsigned u32x4  __attribute__((ext_vector_type(4)));

__device__ __forceinline__ float waveReduce(float v) {
#pragma unroll
    for (int off = 32; off > 0; off >>= 1)
        v += __shfl_down(v, off, 64);
    return v;
}

__device__ __forceinline__ unsigned bf16_rne(float f) {
    unsigned u = __builtin_bit_cast(unsigned, f);
    return (u + 0x7FFFu + ((u >> 16) & 1u)) >> 16;
}
__device__ __forceinline__ unsigned packbf2(float a, float b) {
    return bf16_rne(a) | (bf16_rne(b) << 16);
}

// Async global->LDS DMA, 16 B/lane, lane i lands at ldsbase + i*16.
__device__ __forceinline__ void gload_lds(const uint32_t* g, uint32_t* l) {
    __builtin_amdgcn_global_load_lds(
        (const __attribute__((address_space(1))) void*)(uintptr_t)g,
        (__attribute__((address_space(3))) void*)(unsigned)(uintptr_t)l,
        16, 0, 0);
}

// 224 blocks x 256: [0,24576) row conversions; [24576,57344) bias arrays.
__global__ __launch_bounds__(256) void precompute_kernel(
    const float* __restrict__ p_star, const float* __restrict__ p,
    const float* __restrict__ a, const float* __restrict__ beta_ap,
    const float* __restrict__ gamma_pp, float* __restrict__ ws)
{
    const int g = blockIdx.x * 256 + threadIdx.x;
    if (g < 8) ws[g] = 0.0f;

    if (g < 3 * 8192) {
        const int arr = g >> 13, idx = g & 8191;
        const float* src = arr == 0 ? p_star : (arr == 1 ? p : a);
        const int bfo = arr == 0 ? WS_PSBF : (arr == 1 ? WS_PBF : WS_ABF);
        const int n2o = arr == 0 ? WS_X2PS : (arr == 1 ? WS_Y2P : WS_Y2A);
        const float4* rp = (const float4*)(src + idx * DIM);
        float4 f0 = rp[0], f1 = rp[1], f2 = rp[2], f3 = rp[3];
        float n2 = f0.x*f0.x + f0.y*f0.y + f0.z*f0.z + f0.w*f0.w
                 + f1.x*f1.x + f1.y*f1.y + f1.z*f1.z + f1.w*f1.w
                 + f2.x*f2.x + f2.y*f2.y + f2.z*f2.z + f2.w*f2.w
                 + f3.x*f3.x + f3.y*f3.y + f3.z*f3.z + f3.w*f3.w;
        u32x4 u0 = { packbf2(f0.x, f0.y), packbf2(f0.z, f0.w),
                     packbf2(f1.x, f1.y), packbf2(f1.z, f1.w) };
        u32x4 u1 = { packbf2(f2.x, f2.y), packbf2(f2.z, f2.w),
                     packbf2(f3.x, f3.y), packbf2(f3.z, f3.w) };
        u32x4* dst = (u32x4*)(ws + bfo) + idx * 2;   // 32 B/row, contiguous
        dst[0] = u0; dst[1] = u1;
        ws[n2o + idx] = n2;
    } else if (g < 7 * 8192) {
        const int h = g - 3 * 8192, q = h >> 13, i = h & 8191;
        if      (q == 0) ws[WS_EGC + i] = __expf(gamma_pp[8192 + i]);
        else if (q == 1) ws[WS_EBC + i] = __expf(beta_ap[8192 + i]);
        else if (q == 2) ws[WS_GL2 + i] = gamma_pp[i] * LOG2E;
        else             ws[WS_BL2 + i] = beta_ap[i] * LOG2E;
    }
}

__global__ void main_kernel(
    const float* __restrict__ p_star, const float* __restrict__ p,
    const float* __restrict__ a, const float* __restrict__ beta_ap,
    const float* __restrict__ gamma_pp, const int* __restrict__ edges_pp,
    const int* __restrict__ edges_ap, float* __restrict__ ws,
    float* __restrict__ out)
{
    // sbuf: [0,4096) au (32 tiles x 16 rows x 8 u32); [4096,4608) x2 chunk;
    // [4608,5120) row-bias chunk. 20 KB.
    __shared__ uint32_t sbuf[5120];
    __shared__ float smred[4];
    const int b = blockIdx.x, tid = threadIdx.x, wid = tid >> 6;
    const int lane = tid & 63, quad = lane >> 4, l16 = lane & 15;

    float val = 0.f;
    int slot;

    if (b < NB_AP + NB_PP) {
        const bool isPP = (b >= NB_AP);
        const int  bb   = isPP ? b - NB_AP : b;
        const int  g    = isPP ? 127 - (bb >> 2) : (bb >> 2);  // pp longest-first
        const int  q    = bb & 3;
        const int  s    = (g << 2) + wid;      // this wave's 16-col strip
        slot = isPP ? 0 : 2;

        const uint32_t* Xbf = (const uint32_t*)(ws + WS_PSBF);
        const uint32_t* Ybf = (const uint32_t*)(ws + (isPP ? WS_PBF : WS_ABF));
        const float* x2a = ws + WS_X2PS;
        const float* y2  = ws + (isPP ? WS_Y2P : WS_Y2A);
        const float* gl2 = ws + (isPP ? WS_GL2 : WS_BL2);
        const float* EcA = ws + (isPP ? WS_EGC : WS_EBC);

        const int j = (s << 4) + l16;
        u32x4 bu = {0u, 0u, 0u, 0u};
        if (quad < 2) bu = *(const u32x4*)(Ybf + j * 8 + (quad << 2));
        const bf16x8 bfrag = __builtin_bit_cast(bf16x8, bu);
        const float y2c = y2[j];
        const float Ec  = EcA[j];
        const f32x4 zero4 = {0.f, 0.f, 0.f, 0.f};

        // chunk range for this block: quarter q of the group's tiles
        const int len = isPP ? ((g << 2) + 4) : 512;   // tiles needed by group
        const int nch = (len + CH - 1) / CH;
        const int c0 = (q * nch) >> 2, c1 = ((q + 1) * nch) >> 2;

        float acc = 0.f;
        for (int c = c0; c < c1; ++c) {
            const int t0 = c << 5;
            __syncthreads();   // prior chunk fully consumed before overwrite
            for (int k = wid; k < 20; k += 4) {   // 20 x 1KB async stages
                const uint32_t* gsrc;
                int loff;
                if (k < 16)      { gsrc = Xbf + (t0 << 7) + (k << 8);
                                   loff = k << 8; }
                else if (k < 18) { gsrc = (const uint32_t*)(x2a + (t0 << 4)) + ((k - 16) << 8);
                                   loff = 4096 + ((k - 16) << 8); }
                else             { gsrc = (const uint32_t*)(gl2 + (t0 << 4)) + ((k - 18) << 8);
                                   loff = 4608 + ((k - 18) << 8); }
                gload_lds(gsrc + (lane << 2), &sbuf[loff]);
            }
            __syncthreads();   // barrier drains vmcnt -> staging visible
            const int tF = isPP ? (s < t0 + CH ? s : t0 + CH) : t0 + CH;
            for (int t = t0; t < tF; ++t) {       // full tiles
                const int tl = t - t0;
                u32x4 au = {0u, 0u, 0u, 0u};
                if (quad < 2)
                    au = *(const u32x4*)&sbuf[(tl << 7) + (l16 << 3) + (quad << 2)];
                const f32x4 x24 = *(const f32x4*)((const float*)sbuf + 4096 + (tl << 4) + (quad << 2));
                const f32x4 ag4 = *(const f32x4*)((const float*)sbuf + 4608 + (tl << 4) + (quad << 2));
                f32x4 d = __builtin_amdgcn_mfma_f32_16x16x32_bf16(
                    __builtin_bit_cast(bf16x8, au), bfrag, zero4, 0, 0, 0);
#pragma unroll
                for (int r = 0; r < 4; ++r) {
                    float d2 = fmaf(-2.f, d[r], x24[r] + y2c);
                    d2 = fmaxf(d2, 0.f);
                    acc += __builtin_amdgcn_exp2f(
                        fmaf(-LOG2E, __builtin_amdgcn_sqrtf(d2), ag4[r]));
                }
            }
            if (isPP && s >= t0 && s < t0 + CH) { // diagonal tile, strict j>i
                const int tl = s - t0;
                u32x4 au = {0u, 0u, 0u, 0u};
                if (quad < 2)
                    au = *(const u32x4*)&sbuf[(tl << 7) + (l16 << 3) + (quad << 2)];
                const f32x4 x24 = *(const f32x4*)((const float*)sbuf + 4096 + (tl << 4) + (quad << 2));
                const f32x4 ag4 = *(const f32x4*)((const float*)sbuf + 4608 + (tl << 4) + (quad << 2));
                f32x4 d = __builtin_amdgcn_mfma_f32_16x16x32_bf16(
                    __builtin_bit_cast(bf16x8, au), bfrag, zero4, 0, 0, 0);
#pragma unroll
                for (int r = 0; r < 4; ++r) {
                    float d2 = fmaf(-2.f, d[r], x24[r] + y2c);
                    d2 = fmaxf(d2, 0.f);
                    float term = __builtin_amdgcn_exp2f(
                        fmaf(-LOG2E, __builtin_amdgcn_sqrtf(d2), ag4[r]));
                    if (l16 <= (quad << 2) + r) term = 0.f;
                    acc += term;
                }
            }
        }
        val = acc * Ec;
    } else {
        const int  eb   = b - (NB_AP + NB_PP);
        const bool isPP = (eb < NB_EPP);
        const int  base = (isPP ? eb : eb - NB_EPP) * 256 + tid;  // [0,65536)
        slot = isPP ? 1 : 3;
        float sum = 0.f;
#pragma unroll
        for (int k = 0; k < 4; ++k) {
            const int e = base + k * 65536;
            const float* yrow;
            float bias;
            int e0;
            if (isPP) {
                e0 = edges_pp[e];
                int e1 = edges_pp[NEDGE + e];
                yrow = p + e1 * DIM;
                bias = gamma_pp[e0] + gamma_pp[N_PP + e1];
            } else {
                e0 = edges_ap[e];
                int e1 = edges_ap[NEDGE + e];
                yrow = a + (e1 - N_PP) * DIM;
                bias = beta_ap[e0] + beta_ap[e1];
            }
            const float4* xp = (const float4*)(p_star + e0 * DIM);
            const float4* yp = (const float4*)yrow;
            float d2 = 0.f;
#pragma unroll
            for (int kk = 0; kk < 4; ++kk) {
                float4 xv = xp[kk], yv = yp[kk];
                float dx = xv.x - yv.x, dy = xv.y - yv.y,
                      dz = xv.z - yv.z, dw = xv.w - yv.w;
                d2 += dx*dx + dy*dy + dz*dz + dw*dw;
            }
            sum += bias - __builtin_amdgcn_sqrtf(d2);
        }
        val = sum;
    }

    float wsum = waveReduce(val);
    if ((tid & 63) == 0) smred[wid] = wsum;
    __syncthreads();
    if (tid == 0) {
        atomicAdd(&ws[slot], smred[0] + smred[1] + smred[2] + smred[3]);
        __threadfence();
        unsigned old = atomicAdd((unsigned*)(ws + 4), 1u);
        if (old == NB_TOTAL - 1) {
            float s0 = atomicAdd(&ws[0], 0.f), s1 = atomicAdd(&ws[1], 0.f);
            float s2 = atomicAdd(&ws[2], 0.f), s3 = atomicAdd(&ws[3], 0.f);
            out[0] = 0.5f * (s0 - s1) / (float)N_PP
                   + 0.5f * (s2 - s3) / (float)N_A;
        }
    }
}

extern "C" void kernel_launch(void* const* d_in, const int* in_sizes, int n_in,
                              void* d_out, int out_size, void* d_ws, size_t ws_size,
                              hipStream_t stream) {
    const float* p_star   = (const float*)d_in[0];
    const float* p        = (const float*)d_in[1];
    const float* a        = (const float*)d_in[2];
    const float* beta_ap  = (const float*)d_in[3];
    const float* gamma_pp = (const float*)d_in[4];
    const int*   edges_pp = (const int*)d_in[5];
    const int*   edges_ap = (const int*)d_in[6];

    float* ws  = (float*)d_ws;
    float* out = (float*)d_out;

    hipLaunchKernelGGL(precompute_kernel, dim3(224), dim3(256), 0, stream,
                       p_star, p, a, beta_ap, gamma_pp, ws);
    hipLaunchKernelGGL(main_kernel, dim3(NB_TOTAL), dim3(256), 0, stream,
                       p_star, p, a, beta_ap, gamma_pp, edges_pp, edges_ap, ws, out);
}

// Round 9
// 136.940 us; speedup vs baseline: 1.3721x; 1.0665x over previous
//
#include <hip/hip_runtime.h>
#include <stdint.h>

#define N_PP   8192
#define DIM    16
#define NEDGE  262144
#define LOG2E  1.4426950408889634f

// ---- ws float-unit layout ----
// [0]=nonlink_pp [2]=nonlink_ap [4]=counter(uint)
// [8..136)  pp edge per-block sums (pure writes, no init needed)
// [136..264) ap edge per-block sums
// data regions from float 512:
#define WS_EDGE  8
#define WS_PSBF  512
#define WS_PBF   (WS_PSBF + 65536)
#define WS_ABF   (WS_PBF  + 65536)
#define WS_X2PS  (WS_ABF  + 65536)
#define WS_Y2P   (WS_X2PS + 8192)
#define WS_Y2A   (WS_Y2P  + 8192)
#define WS_EGC   (WS_Y2A  + 8192)   // exp(gamma_pp[8192+j])
#define WS_EBC   (WS_EGC  + 8192)   // exp(beta_ap[8192+j])
#define WS_GL2   (WS_EBC  + 8192)   // gamma_pp[i]*LOG2E
#define WS_BL2   (WS_GL2  + 8192)   // beta_ap[i]*LOG2E

// Main grid: one block = one uniform quantum = (col-group g of 128 cols,
// 32-tile chunk c). ap: 64 groups x 16 chunks = 1024. pp: group g needs
// ceil((8g+8)/32) = (g>>2)+1 chunks -> 544. Wave w covers strips 8g+2w, +1.
#define NQ_AP  1024
#define NQ_PP  544
#define NB_MAT (NQ_AP + NQ_PP)

typedef short    bf16x8 __attribute__((ext_vector_type(8)));
typedef float    f32x4  __attribute__((ext_vector_type(4)));
typedef unsigned u32x4  __attribute__((ext_vector_type(4)));

__device__ __forceinline__ float waveReduce(float v) {
#pragma unroll
    for (int off = 32; off > 0; off >>= 1)
        v += __shfl_down(v, off, 64);
    return v;
}

__device__ __forceinline__ unsigned bf16_rne(float f) {
    unsigned u = __builtin_bit_cast(unsigned, f);
    return (u + 0x7FFFu + ((u >> 16) & 1u)) >> 16;
}
__device__ __forceinline__ unsigned packbf2(float a, float b) {
    return bf16_rne(a) | (bf16_rne(b) << 16);
}

// Async global->LDS DMA, 16 B/lane, lane i lands at ldsbase + i*16.
__device__ __forceinline__ void gload_lds(const uint32_t* g, uint32_t* l) {
    __builtin_amdgcn_global_load_lds(
        (const __attribute__((address_space(1))) void*)(uintptr_t)g,
        (__attribute__((address_space(3))) void*)(unsigned)(uintptr_t)l,
        16, 0, 0);
}

// K1: 480 blocks. [0,224): conversions + bias arrays + zero accums.
// [224,480): 256 edge blocks (128 pp + 128 ap, 2048 edges each) -> pure
// per-block writes to ws[WS_EDGE + eb].
__global__ __launch_bounds__(256) void pre_kernel(
    const float* __restrict__ p_star, const float* __restrict__ p,
    const float* __restrict__ a, const float* __restrict__ beta_ap,
    const float* __restrict__ gamma_pp, const int* __restrict__ edges_pp,
    const int* __restrict__ edges_ap, float* __restrict__ ws)
{
    const int b = blockIdx.x, tid = threadIdx.x;

    if (b < 224) {
        const int g = b * 256 + tid;
        if (g < 8) ws[g] = 0.0f;
        if (g < 3 * 8192) {
            const int arr = g >> 13, idx = g & 8191;
            const float* src = arr == 0 ? p_star : (arr == 1 ? p : a);
            const int bfo = arr == 0 ? WS_PSBF : (arr == 1 ? WS_PBF : WS_ABF);
            const int n2o = arr == 0 ? WS_X2PS : (arr == 1 ? WS_Y2P : WS_Y2A);
            const float4* rp = (const float4*)(src + idx * DIM);
            float4 f0 = rp[0], f1 = rp[1], f2 = rp[2], f3 = rp[3];
            float n2 = f0.x*f0.x + f0.y*f0.y + f0.z*f0.z + f0.w*f0.w
                     + f1.x*f1.x + f1.y*f1.y + f1.z*f1.z + f1.w*f1.w
                     + f2.x*f2.x + f2.y*f2.y + f2.z*f2.z + f2.w*f2.w
                     + f3.x*f3.x + f3.y*f3.y + f3.z*f3.z + f3.w*f3.w;
            u32x4 u0 = { packbf2(f0.x, f0.y), packbf2(f0.z, f0.w),
                         packbf2(f1.x, f1.y), packbf2(f1.z, f1.w) };
            u32x4 u1 = { packbf2(f2.x, f2.y), packbf2(f2.z, f2.w),
                         packbf2(f3.x, f3.y), packbf2(f3.z, f3.w) };
            u32x4* dst = (u32x4*)(ws + bfo) + idx * 2;   // 32 B/row contiguous
            dst[0] = u0; dst[1] = u1;
            ws[n2o + idx] = n2;
        } else if (g < 7 * 8192) {
            const int h = g - 3 * 8192, q = h >> 13, i = h & 8191;
            if      (q == 0) ws[WS_EGC + i] = __expf(gamma_pp[8192 + i]);
            else if (q == 1) ws[WS_EBC + i] = __expf(beta_ap[8192 + i]);
            else if (q == 2) ws[WS_GL2 + i] = gamma_pp[i] * LOG2E;
            else             ws[WS_BL2 + i] = beta_ap[i] * LOG2E;
        }
    } else {
        __shared__ float smred[4];
        const int  eb   = b - 224;            // 0..255
        const bool isPP = (eb < 128);
        const int  base = (isPP ? eb : eb - 128) * 2048;
        float sum = 0.f;
#pragma unroll
        for (int k = 0; k < 8; ++k) {
            const int e = base + k * 256 + tid;
            const float* yrow;
            float bias;
            int e0;
            if (isPP) {
                e0 = edges_pp[e];
                int e1 = edges_pp[NEDGE + e];
                yrow = p + e1 * DIM;
                bias = gamma_pp[e0] + gamma_pp[N_PP + e1];
            } else {
                e0 = edges_ap[e];
                int e1 = edges_ap[NEDGE + e];
                yrow = a + (e1 - N_PP) * DIM;
                bias = beta_ap[e0] + beta_ap[e1];
            }
            const float4* xp = (const float4*)(p_star + e0 * DIM);
            const float4* yp = (const float4*)yrow;
            float d2 = 0.f;
#pragma unroll
            for (int kk = 0; kk < 4; ++kk) {
                float4 xv = xp[kk], yv = yp[kk];
                float dx = xv.x - yv.x, dy = xv.y - yv.y,
                      dz = xv.z - yv.z, dw = xv.w - yv.w;
                d2 += dx*dx + dy*dy + dz*dz + dw*dw;
            }
            sum += bias - __builtin_amdgcn_sqrtf(d2);
        }
        float wsum = waveReduce(sum);
        if ((tid & 63) == 0) smred[tid >> 6] = wsum;
        __syncthreads();
        if (tid == 0)
            ws[WS_EDGE + eb] = smred[0] + smred[1] + smred[2] + smred[3];
    }
}

__global__ void main_kernel(float* __restrict__ ws, float* __restrict__ out)
{
    // sbuf: [0,4096) 32 tiles x 16 rows x 8 u32; [4096,4608) x2; [4608,5120) bias
    __shared__ uint32_t sbuf[5120];
    __shared__ float smred[4];
    const int b = blockIdx.x, tid = threadIdx.x, wid = tid >> 6;
    const int lane = tid & 63, quad = lane >> 4, l16 = lane & 15;

    // ---- decode quantum -> (isPP, group g, chunk c) ----
    const bool isPP = (b >= NQ_AP);
    int g, c;
    if (!isPP) { g = b >> 4; c = b & 15; }
    else {
        const int qq = b - NQ_AP;
        int bnd = 0;
        while (2 * (bnd + 1) * (bnd + 2) <= qq) ++bnd;   // band: groups 4bnd..4bnd+3
        const int r = qq - 2 * bnd * (bnd + 1);
        g = 4 * bnd + r / (bnd + 1);
        c = r % (bnd + 1);
    }
    const int t0 = c << 5;

    const uint32_t* Xbf = (const uint32_t*)(ws + WS_PSBF);
    const uint32_t* Ybf = (const uint32_t*)(ws + (isPP ? WS_PBF : WS_ABF));
    const float* x2a = ws + WS_X2PS;
    const float* y2  = ws + (isPP ? WS_Y2P : WS_Y2A);
    const float* gl2 = ws + (isPP ? WS_GL2 : WS_BL2);
    const float* EcA = ws + (isPP ? WS_EGC : WS_EBC);

    // ---- per-wave: two adjacent 16-col strips ----
    const int sA = (g << 3) + (wid << 1);
    bf16x8 bfrag[2];
    float  y2c[2], Ec[2];
#pragma unroll
    for (int ss = 0; ss < 2; ++ss) {
        const int j = ((sA + ss) << 4) + l16;
        u32x4 bu = {0u, 0u, 0u, 0u};
        if (quad < 2) bu = *(const u32x4*)(Ybf + j * 8 + (quad << 2));
        bfrag[ss] = __builtin_bit_cast(bf16x8, bu);
        y2c[ss] = y2[j];
        Ec[ss]  = EcA[j];
    }

    // ---- stage 32 tiles (16 KB rows + 2 KB x2 + 2 KB bias), async DMA ----
    for (int k = wid; k < 20; k += 4) {
        const uint32_t* gsrc;
        int loff;
        if (k < 16)      { gsrc = Xbf + (t0 << 7) + (k << 8);            loff = k << 8; }
        else if (k < 18) { gsrc = (const uint32_t*)(x2a + (t0 << 4)) + ((k - 16) << 8);
                           loff = 4096 + ((k - 16) << 8); }
        else             { gsrc = (const uint32_t*)(gl2 + (t0 << 4)) + ((k - 18) << 8);
                           loff = 4608 + ((k - 18) << 8); }
        gload_lds(gsrc + (lane << 2), &sbuf[loff]);
    }
    __syncthreads();   // drains DMA, staging visible

    const f32x4 zero4 = {0.f, 0.f, 0.f, 0.f};
    float acc[2] = {0.f, 0.f};
    const int tHi = isPP ? (sA + 1 < t0 + 32 ? sA + 2 : t0 + 32) : t0 + 32;
    for (int t = t0; t < tHi; ++t) {
        const int tl = t - t0;
        // aliased unconditional b128: quads 2,3 re-read quads 0,1's valid
        // finite data; it multiplies bfrag's zero upper half -> contributes 0.
        const u32x4 au = *(const u32x4*)&sbuf[(tl << 7) + (l16 << 3) + ((quad & 1) << 2)];
        const f32x4 x24 = *(const f32x4*)((const float*)sbuf + 4096 + (tl << 4) + (quad << 2));
        const f32x4 ag4 = *(const f32x4*)((const float*)sbuf + 4608 + (tl << 4) + (quad << 2));
#pragma unroll
        for (int ss = 0; ss < 2; ++ss) {
            const int s = sA + ss;
            if (isPP && t > s) continue;            // wave-uniform
            f32x4 d = __builtin_amdgcn_mfma_f32_16x16x32_bf16(
                __builtin_bit_cast(bf16x8, au), bfrag[ss], zero4, 0, 0, 0);
            if (!isPP || t < s) {                   // full tile
#pragma unroll
                for (int r = 0; r < 4; ++r) {
                    float d2 = fmaf(-2.f, d[r], x24[r] + y2c[ss]);
                    d2 = fmaxf(d2, 0.f);
                    acc[ss] += __builtin_amdgcn_exp2f(
                        fmaf(-LOG2E, __builtin_amdgcn_sqrtf(d2), ag4[r]));
                }
            } else {                                // diagonal tile, strict j>i
#pragma unroll
                for (int r = 0; r < 4; ++r) {
                    float d2 = fmaf(-2.f, d[r], x24[r] + y2c[ss]);
                    d2 = fmaxf(d2, 0.f);
                    float term = __builtin_amdgcn_exp2f(
                        fmaf(-LOG2E, __builtin_amdgcn_sqrtf(d2), ag4[r]));
                    if (l16 <= (quad << 2) + r) term = 0.f;
                    acc[ss] += term;
                }
            }
        }
    }
    const float val = acc[0] * Ec[0] + acc[1] * Ec[1];

    float wsum = waveReduce(val);
    if ((tid & 63) == 0) smred[wid] = wsum;
    __syncthreads();
    if (tid == 0) {
        atomicAdd(&ws[isPP ? 2 : 0], smred[0] + smred[1] + smred[2] + smred[3]);
        __threadfence();
        unsigned old = atomicAdd((unsigned*)(ws + 4), 1u);
        if (old == NB_MAT - 1) {
            float s0 = atomicAdd(&ws[0], 0.f);    // nonlink_pp
            float s2 = atomicAdd(&ws[2], 0.f);    // nonlink_ap
            float lpp = 0.f, lap = 0.f;
            for (int i = 0; i < 128; i += 4) {
                const float4 v = *(const float4*)(ws + WS_EDGE + i);
                const float4 u = *(const float4*)(ws + WS_EDGE + 128 + i);
                lpp += v.x + v.y + v.z + v.w;
                lap += u.x + u.y + u.z + u.w;
            }
            out[0] = 0.5f * (s0 - lpp) / (float)N_PP
                   + 0.5f * (s2 - lap) / (float)N_PP;
        }
    }
}

extern "C" void kernel_launch(void* const* d_in, const int* in_sizes, int n_in,
                              void* d_out, int out_size, void* d_ws, size_t ws_size,
                              hipStream_t stream) {
    const float* p_star   = (const float*)d_in[0];
    const float* p        = (const float*)d_in[1];
    const float* a        = (const float*)d_in[2];
    const float* beta_ap  = (const float*)d_in[3];
    const float* gamma_pp = (const float*)d_in[4];
    const int*   edges_pp = (const int*)d_in[5];
    const int*   edges_ap = (const int*)d_in[6];

    float* ws  = (float*)d_ws;
    float* out = (float*)d_out;

    hipLaunchKernelGGL(pre_kernel, dim3(480), dim3(256), 0, stream,
                       p_star, p, a, beta_ap, gamma_pp, edges_pp, edges_ap, ws);
    hipLaunchKernelGGL(main_kernel, dim3(NB_MAT), dim3(256), 0, stream, ws, out);
}